// Round 2
// baseline (88.403 us; speedup 1.0000x reference)
//
#include <hip/hip_runtime.h>
#include <hip/hip_bf16.h>

typedef short bf16x8 __attribute__((ext_vector_type(8)));
typedef float f32x4  __attribute__((ext_vector_type(4)));
typedef unsigned short u16;

// float -> bf16 round-to-nearest-even
static __device__ __forceinline__ u16 f2bf(float f) {
    unsigned u = __float_as_uint(f);
    u += 0x7FFFu + ((u >> 16) & 1u);
    return (u16)(u >> 16);
}
static __device__ __forceinline__ float bf2f(u16 b) {
    return __uint_as_float(((unsigned)b) << 16);
}
static __device__ __forceinline__ unsigned pack2(float lo, float hi) {
    return (unsigned)f2bf(lo) | ((unsigned)f2bf(hi) << 16);
}

// ---------------------------------------------------------------------------
// Kernel 1: W' [256 cols][128 k] bf16. W'[c][k] = W1[k][c] (c<128, P half),
// W1[128+k][c-128] (Q half). 16B-contiguous per (c, 8k) fragment.
// ---------------------------------------------------------------------------
__global__ void prep_w(const float* __restrict__ W1, u16* __restrict__ Wl) {
    int idx = blockIdx.x * 256 + threadIdx.x;   // over W1 flat [256][128]
    if (idx >= 256 * 128) return;
    int r = idx >> 7;     // W1 row 0..255
    int q = idx & 127;    // W1 col 0..127
    int k = (r < 128) ? r : (r - 128);
    int c = (r < 128) ? q : (q + 128);
    Wl[c * 128 + k] = f2bf(W1[idx]);
}

// ---------------------------------------------------------------------------
// Kernel 2: PQ[m][0:256] = z[m][0:128] @ W'  (bf16 MFMA, fp32 accum)
// Swapped operands: D[c][m] = sum_k W'[c][k] * z[m][k]  -> C/D "row" dim is
// the W'-column axis, so each lane holds 4 CONSECUTIVE output cols of ONE
// node -> packed 8B stores instead of scattered 2B stores.
// ---------------------------------------------------------------------------
#define BM 128
__global__ __launch_bounds__(256, 2) void node_gemm(
    const float* __restrict__ z,   // [M][128] fp32
    const u16*   __restrict__ Wl,  // [256][128] bf16
    u16*         __restrict__ PQ,  // [M][256] bf16
    int M)
{
    __shared__ char As[BM * 256];  // BM rows x 128 bf16 (256 B/row), swizzled
    const int tid  = threadIdx.x;
    const int lane = tid & 63;
    const int wave = tid >> 6;
    const int m0   = blockIdx.x * BM;

    // ---- stage A: fp32 -> bf16, swizzled write ----
    #pragma unroll
    for (int i = 0; i < (BM * 32) / 256; ++i) {
        int ci  = tid + i * 256;        // 32 float4-chunks per row
        int row = ci >> 5;
        int c4  = ci & 31;
        float4 v = make_float4(0.f, 0.f, 0.f, 0.f);
        if (m0 + row < M)
            v = *(const float4*)(z + (size_t)(m0 + row) * 128 + c4 * 4);
        ushort4 b;
        b.x = f2bf(v.x); b.y = f2bf(v.y); b.z = f2bf(v.z); b.w = f2bf(v.w);
        int byte = row * 256 + ((c4 * 8) ^ ((row & 7) << 4));
        *(ushort4*)(As + byte) = b;
    }
    __syncthreads();

    f32x4 acc[8][4];   // [mf][ci]
    #pragma unroll
    for (int mf = 0; mf < 8; ++mf)
        #pragma unroll
        for (int ci = 0; ci < 4; ++ci)
            acc[mf][ci] = (f32x4){0.f, 0.f, 0.f, 0.f};

    const int g  = lane >> 4;     // k-group 0..3
    const int ln = lane & 15;     // A-row (W' col) / B-col (node) lane index
    const int c0 = wave * 64;     // this wave's W'-column slice

    #pragma unroll
    for (int ks = 0; ks < 4; ++ks) {
        bf16x8 a[4];
        #pragma unroll
        for (int ci = 0; ci < 4; ++ci)
            a[ci] = *(const bf16x8*)(Wl + (c0 + ci * 16 + ln) * 128 + ks * 32 + g * 8);
        #pragma unroll
        for (int mf = 0; mf < 8; ++mf) {
            int row  = mf * 16 + ln;
            int byte = row * 256 + ((ks * 64 + g * 16) ^ ((row & 7) << 4));
            bf16x8 b = *(const bf16x8*)(As + byte);
            #pragma unroll
            for (int ci = 0; ci < 4; ++ci)
                acc[mf][ci] = __builtin_amdgcn_mfma_f32_16x16x32_bf16(
                    a[ci], b, acc[mf][ci], 0, 0, 0);
        }
    }

    // ---- C write: lane holds node = m0+mf*16+ln, cols c0+ci*16+g*4+{0..3}
    #pragma unroll
    for (int mf = 0; mf < 8; ++mf) {
        int node = m0 + mf * 16 + ln;
        if (node < M) {
            #pragma unroll
            for (int ci = 0; ci < 4; ++ci) {
                uint2 w;
                w.x = pack2(acc[mf][ci][0], acc[mf][ci][1]);
                w.y = pack2(acc[mf][ci][2], acc[mf][ci][3]);
                *(uint2*)(PQ + (size_t)node * 256 + c0 + ci * 16 + g * 4) = w;
            }
        }
    }
}

// ---------------------------------------------------------------------------
// Kernel 3: out[e] = relu(P[s] + Q[d] + b1) . W2 + b2.
// 16 lanes x 2 edges per thread: 4 independent 16B gathers in flight.
// ---------------------------------------------------------------------------
__global__ __launch_bounds__(256) void edge_mlp(
    const int* __restrict__ ei,    // [2][E] int32
    const u16* __restrict__ PQ,    // [M][256] bf16
    const float* __restrict__ b1,  // [128]
    const float* __restrict__ W2,  // [128]
    const float* __restrict__ b2,  // [1]
    float* __restrict__ out,       // [E]
    int E)
{
    int gid  = blockIdx.x * 256 + threadIdx.x;
    int e0   = (gid >> 4) * 2;
    int sub  = gid & 15;
    if (e0 >= E) return;
    bool two = (e0 + 1) < E;

    int2 ss, dd;
    if (two) {
        ss = *(const int2*)(ei + e0);
        dd = *(const int2*)(ei + E + e0);
    } else {
        ss.x = ei[e0];     ss.y = ss.x;
        dd.x = ei[E + e0]; dd.y = dd.x;
    }

    uint4 p0 = *(const uint4*)(PQ + (size_t)ss.x * 256 + sub * 8);
    uint4 q0 = *(const uint4*)(PQ + (size_t)dd.x * 256 + 128 + sub * 8);
    uint4 p1 = *(const uint4*)(PQ + (size_t)ss.y * 256 + sub * 8);
    uint4 q1 = *(const uint4*)(PQ + (size_t)dd.y * 256 + 128 + sub * 8);

    float4 b1a = *(const float4*)(b1 + sub * 8);
    float4 b1b = *(const float4*)(b1 + sub * 8 + 4);
    float4 w2a = *(const float4*)(W2 + sub * 8);
    float4 w2b = *(const float4*)(W2 + sub * 8 + 4);
    float bb[8] = {b1a.x, b1a.y, b1a.z, b1a.w, b1b.x, b1b.y, b1b.z, b1b.w};
    float ww[8] = {w2a.x, w2a.y, w2a.z, w2a.w, w2b.x, w2b.y, w2b.z, w2b.w};

    const u16* p0u = (const u16*)&p0;
    const u16* q0u = (const u16*)&q0;
    const u16* p1u = (const u16*)&p1;
    const u16* q1u = (const u16*)&q1;

    float acc0 = 0.f, acc1 = 0.f;
    #pragma unroll
    for (int j = 0; j < 8; ++j) {
        float h0 = bf2f(p0u[j]) + bf2f(q0u[j]) + bb[j];
        float h1 = bf2f(p1u[j]) + bf2f(q1u[j]) + bb[j];
        acc0 = fmaf(fmaxf(h0, 0.f), ww[j], acc0);
        acc1 = fmaf(fmaxf(h1, 0.f), ww[j], acc1);
    }
    #pragma unroll
    for (int m = 1; m < 16; m <<= 1) {
        acc0 += __shfl_xor(acc0, m);
        acc1 += __shfl_xor(acc1, m);
    }

    if (sub == 0) {
        float bias = b2[0];
        if (two) {
            float2 o = make_float2(acc0 + bias, acc1 + bias);
            *(float2*)(out + e0) = o;
        } else {
            out[e0] = acc0 + bias;
        }
    }
}

// ---------------------------------------------------------------------------
extern "C" void kernel_launch(void* const* d_in, const int* in_sizes, int n_in,
                              void* d_out, int out_size, void* d_ws, size_t ws_size,
                              hipStream_t stream) {
    const float* z  = (const float*)d_in[0];
    const int*   ei = (const int*)d_in[1];
    const float* W1 = (const float*)d_in[2];
    const float* b1 = (const float*)d_in[3];
    const float* W2 = (const float*)d_in[4];
    const float* b2 = (const float*)d_in[5];
    float* out = (float*)d_out;

    const int M = in_sizes[0] / 128;   // 100000 nodes
    const int E = in_sizes[1] / 2;     // 640000 edges

    u16* Wl = (u16*)d_ws;                          // 64 KB
    u16* PQ = (u16*)((char*)d_ws + 65536);         // M*256*2 B = 51.2 MB

    hipLaunchKernelGGL(prep_w, dim3(128), dim3(256), 0, stream, W1, Wl);

    int gb = (M + BM - 1) / BM;
    hipLaunchKernelGGL(node_gemm, dim3(gb), dim3(256), 0, stream, z, Wl, PQ, M);

    int eb = (E * 8 + 255) / 256;
    hipLaunchKernelGGL(edge_mlp, dim3(eb), dim3(256), 0, stream,
                       ei, PQ, b1, W2, b2, out, E);
}

// Round 3
// 80.967 us; speedup vs baseline: 1.0918x; 1.0918x over previous
//
#include <hip/hip_runtime.h>
#include <hip/hip_bf16.h>

typedef short bf16x8 __attribute__((ext_vector_type(8)));
typedef float f32x4  __attribute__((ext_vector_type(4)));
typedef unsigned short u16;

// float -> bf16 round-to-nearest-even
static __device__ __forceinline__ u16 f2bf(float f) {
    unsigned u = __float_as_uint(f);
    u += 0x7FFFu + ((u >> 16) & 1u);
    return (u16)(u >> 16);
}
static __device__ __forceinline__ float bf2f(u16 b) {
    return __uint_as_float(((unsigned)b) << 16);
}
static __device__ __forceinline__ unsigned pack2(float lo, float hi) {
    return (unsigned)f2bf(lo) | ((unsigned)f2bf(hi) << 16);
}

// ---------------------------------------------------------------------------
// Kernel 1: W' [256 cols][128 k] bf16. W'[c][k] = W1[k][c] (c<128, P half),
// W1[128+k][c-128] (Q half).
// ---------------------------------------------------------------------------
__global__ void prep_w(const float* __restrict__ W1, u16* __restrict__ Wl) {
    int idx = blockIdx.x * 256 + threadIdx.x;   // over W1 flat [256][128]
    if (idx >= 256 * 128) return;
    int r = idx >> 7;     // W1 row 0..255
    int q = idx & 127;    // W1 col 0..127
    int k = (r < 128) ? r : (r - 128);
    int c = (r < 128) ? q : (q + 128);
    Wl[c * 128 + k] = f2bf(W1[idx]);
}

// ---------------------------------------------------------------------------
// Kernel 2: persistent double-buffered GEMM.
// PQ[m][c] = sum_k z[m][k]*W'[c][k]  (+ b1[c] for c<128), bf16 out.
// BM=64 rows/tile, 512 persistent blocks x ~3 tiles, LDS 2x16KB dbuf.
// Swapped MFMA operands: lane holds 4 consecutive cols of one node.
// ---------------------------------------------------------------------------
#define BM 64
__global__ __launch_bounds__(256, 2) void node_gemm(
    const float* __restrict__ z,   // [M][128] fp32
    const u16*   __restrict__ Wl,  // [256][128] bf16
    const float* __restrict__ b1,  // [128]
    u16*         __restrict__ PQ,  // [M][256] bf16
    int M, int ntiles)
{
    __shared__ char As[2][BM * 256];  // 64 rows x 256B (128 bf16), swizzled
    const int tid  = threadIdx.x;
    const int lane = tid & 63;
    const int wave = tid >> 6;
    const int g    = lane >> 4;     // k-group 0..3
    const int ln   = lane & 15;
    const int c0   = wave * 64;     // this wave's W'-column slice

    int t = blockIdx.x;
    if (t >= ntiles) return;

    // bias fragment (constant across tiles): cols c0+ci*16+g*4 .. +3
    float4 bias[4];
    #pragma unroll
    for (int ci = 0; ci < 4; ++ci) {
        int col = c0 + ci * 16 + g * 4;
        bias[ci] = (col < 128) ? *(const float4*)(b1 + col)
                               : make_float4(0.f, 0.f, 0.f, 0.f);
    }

    float4 r[8];   // staging regs: 8 float4-chunks/thread (64 rows x 32 ch)

    // ---- prologue: load + stage tile t into buf 0 ----
    {
        int m0 = t * BM;
        #pragma unroll
        for (int i = 0; i < 8; ++i) {
            int ci = tid + i * 256, row = ci >> 5, c4 = ci & 31;
            r[i] = make_float4(0.f, 0.f, 0.f, 0.f);
            if (m0 + row < M)
                r[i] = *(const float4*)(z + (size_t)(m0 + row) * 128 + c4 * 4);
        }
        #pragma unroll
        for (int i = 0; i < 8; ++i) {
            int ci = tid + i * 256, row = ci >> 5, c4 = ci & 31;
            ushort4 b;
            b.x = f2bf(r[i].x); b.y = f2bf(r[i].y);
            b.z = f2bf(r[i].z); b.w = f2bf(r[i].w);
            *(ushort4*)(As[0] + row * 256 + ((c4 * 8) ^ ((row & 7) << 4))) = b;
        }
    }
    __syncthreads();

    int cur = 0;
    while (true) {
        int next = t + gridDim.x;
        bool have = (next < ntiles);

        // ---- issue next tile's global loads (latency hides under MFMA) ----
        if (have) {
            int m0 = next * BM;
            #pragma unroll
            for (int i = 0; i < 8; ++i) {
                int ci = tid + i * 256, row = ci >> 5, c4 = ci & 31;
                r[i] = make_float4(0.f, 0.f, 0.f, 0.f);
                if (m0 + row < M)
                    r[i] = *(const float4*)(z + (size_t)(m0 + row) * 128 + c4 * 4);
            }
        }

        // ---- compute tile t from As[cur] ----
        f32x4 acc[4][4];   // [mf][ci]
        #pragma unroll
        for (int mf = 0; mf < 4; ++mf)
            #pragma unroll
            for (int ci = 0; ci < 4; ++ci)
                acc[mf][ci] = (f32x4){0.f, 0.f, 0.f, 0.f};

        #pragma unroll
        for (int ks = 0; ks < 4; ++ks) {
            bf16x8 a[4];
            #pragma unroll
            for (int ci = 0; ci < 4; ++ci)
                a[ci] = *(const bf16x8*)(Wl + (c0 + ci * 16 + ln) * 128 + ks * 32 + g * 8);
            #pragma unroll
            for (int mf = 0; mf < 4; ++mf) {
                int row  = mf * 16 + ln;
                int byte = row * 256 + ((ks * 64 + g * 16) ^ ((row & 7) << 4));
                bf16x8 b = *(const bf16x8*)(As[cur] + byte);
                #pragma unroll
                for (int ci = 0; ci < 4; ++ci)
                    acc[mf][ci] = __builtin_amdgcn_mfma_f32_16x16x32_bf16(
                        a[ci], b, acc[mf][ci], 0, 0, 0);
            }
        }

        // ---- stage next tile into the other buffer (waits its loads) ----
        if (have) {
            #pragma unroll
            for (int i = 0; i < 8; ++i) {
                int ci = tid + i * 256, row = ci >> 5, c4 = ci & 31;
                ushort4 b;
                b.x = f2bf(r[i].x); b.y = f2bf(r[i].y);
                b.z = f2bf(r[i].z); b.w = f2bf(r[i].w);
                *(ushort4*)(As[cur ^ 1] + row * 256 + ((c4 * 8) ^ ((row & 7) << 4))) = b;
            }
        }

        // ---- store C for tile t (after CVT so its vmcnt isn't drained) ----
        {
            int m0 = t * BM;
            #pragma unroll
            for (int mf = 0; mf < 4; ++mf) {
                int node = m0 + mf * 16 + ln;
                if (node < M) {
                    #pragma unroll
                    for (int ci = 0; ci < 4; ++ci) {
                        uint2 w;
                        w.x = pack2(acc[mf][ci][0] + bias[ci].x,
                                    acc[mf][ci][1] + bias[ci].y);
                        w.y = pack2(acc[mf][ci][2] + bias[ci].z,
                                    acc[mf][ci][3] + bias[ci].w);
                        *(uint2*)(PQ + (size_t)node * 256 + c0 + ci * 16 + g * 4) = w;
                    }
                }
            }
        }

        if (!have) break;
        __syncthreads();
        cur ^= 1;
        t = next;
    }
}

// ---------------------------------------------------------------------------
// Kernel 3: out[e] = relu(P[s] + Q[d]) . W2 + b2   (b1 pre-folded into P).
// 16 lanes x 4 edges per thread: 8 independent 16B gathers in flight.
// ---------------------------------------------------------------------------
__global__ __launch_bounds__(256) void edge_mlp(
    const int* __restrict__ ei,    // [2][E] int32
    const u16* __restrict__ PQ,    // [M][256] bf16
    const float* __restrict__ W2,  // [128]
    const float* __restrict__ b2,  // [1]
    float* __restrict__ out,       // [E]
    int E)
{
    int gid = blockIdx.x * 256 + threadIdx.x;
    int e0  = (gid >> 4) * 4;
    int sub = gid & 15;
    if (e0 >= E) return;

    float4 w2a = *(const float4*)(W2 + sub * 8);
    float4 w2b = *(const float4*)(W2 + sub * 8 + 4);
    float ww[8] = {w2a.x, w2a.y, w2a.z, w2a.w, w2b.x, w2b.y, w2b.z, w2b.w};
    float bias = b2[0];

    if (e0 + 3 < E) {
        int4 s = *(const int4*)(ei + e0);
        int4 d = *(const int4*)(ei + E + e0);
        uint4 p0 = *(const uint4*)(PQ + (size_t)s.x * 256 + sub * 8);
        uint4 p1 = *(const uint4*)(PQ + (size_t)s.y * 256 + sub * 8);
        uint4 p2 = *(const uint4*)(PQ + (size_t)s.z * 256 + sub * 8);
        uint4 p3 = *(const uint4*)(PQ + (size_t)s.w * 256 + sub * 8);
        uint4 q0 = *(const uint4*)(PQ + (size_t)d.x * 256 + 128 + sub * 8);
        uint4 q1 = *(const uint4*)(PQ + (size_t)d.y * 256 + 128 + sub * 8);
        uint4 q2 = *(const uint4*)(PQ + (size_t)d.z * 256 + 128 + sub * 8);
        uint4 q3 = *(const uint4*)(PQ + (size_t)d.w * 256 + 128 + sub * 8);

        float a0 = 0.f, a1 = 0.f, a2 = 0.f, a3 = 0.f;
        const u16* pu0 = (const u16*)&p0; const u16* qu0 = (const u16*)&q0;
        const u16* pu1 = (const u16*)&p1; const u16* qu1 = (const u16*)&q1;
        const u16* pu2 = (const u16*)&p2; const u16* qu2 = (const u16*)&q2;
        const u16* pu3 = (const u16*)&p3; const u16* qu3 = (const u16*)&q3;
        #pragma unroll
        for (int j = 0; j < 8; ++j) {
            a0 = fmaf(fmaxf(bf2f(pu0[j]) + bf2f(qu0[j]), 0.f), ww[j], a0);
            a1 = fmaf(fmaxf(bf2f(pu1[j]) + bf2f(qu1[j]), 0.f), ww[j], a1);
            a2 = fmaf(fmaxf(bf2f(pu2[j]) + bf2f(qu2[j]), 0.f), ww[j], a2);
            a3 = fmaf(fmaxf(bf2f(pu3[j]) + bf2f(qu3[j]), 0.f), ww[j], a3);
        }
        #pragma unroll
        for (int m = 1; m < 16; m <<= 1) {
            a0 += __shfl_xor(a0, m);
            a1 += __shfl_xor(a1, m);
            a2 += __shfl_xor(a2, m);
            a3 += __shfl_xor(a3, m);
        }
        if (sub == 0) {
            float4 o = make_float4(a0 + bias, a1 + bias, a2 + bias, a3 + bias);
            *(float4*)(out + e0) = o;
        }
    } else {
        for (int k = 0; k < 4; ++k) {
            int e = e0 + k;
            if (e >= E) break;
            int sn = ei[e], dn = ei[E + e];
            uint4 p = *(const uint4*)(PQ + (size_t)sn * 256 + sub * 8);
            uint4 q = *(const uint4*)(PQ + (size_t)dn * 256 + 128 + sub * 8);
            const u16* pu = (const u16*)&p; const u16* qu = (const u16*)&q;
            float a = 0.f;
            #pragma unroll
            for (int j = 0; j < 8; ++j)
                a = fmaf(fmaxf(bf2f(pu[j]) + bf2f(qu[j]), 0.f), ww[j], a);
            #pragma unroll
            for (int m = 1; m < 16; m <<= 1) a += __shfl_xor(a, m);
            if (sub == 0) out[e] = a + bias;
        }
    }
}

// ---------------------------------------------------------------------------
extern "C" void kernel_launch(void* const* d_in, const int* in_sizes, int n_in,
                              void* d_out, int out_size, void* d_ws, size_t ws_size,
                              hipStream_t stream) {
    const float* z  = (const float*)d_in[0];
    const int*   ei = (const int*)d_in[1];
    const float* W1 = (const float*)d_in[2];
    const float* b1 = (const float*)d_in[3];
    const float* W2 = (const float*)d_in[4];
    const float* b2 = (const float*)d_in[5];
    float* out = (float*)d_out;

    const int M = in_sizes[0] / 128;   // 100000 nodes
    const int E = in_sizes[1] / 2;     // 640000 edges

    u16* Wl = (u16*)d_ws;                          // 64 KB
    u16* PQ = (u16*)((char*)d_ws + 65536);         // M*256*2 B = 51.2 MB

    hipLaunchKernelGGL(prep_w, dim3(128), dim3(256), 0, stream, W1, Wl);

    int ntiles = (M + BM - 1) / BM;
    int gb = ntiles < 512 ? ntiles : 512;
    hipLaunchKernelGGL(node_gemm, dim3(gb), dim3(256), 0, stream,
                       z, Wl, b1, PQ, M, ntiles);

    int eb = ((E + 3) / 4 * 16 + 255) / 256;
    hipLaunchKernelGGL(edge_mlp, dim3(eb), dim3(256), 0, stream,
                       ei, PQ, W2, b2, out, E);
}

// Round 4
// 74.128 us; speedup vs baseline: 1.1926x; 1.0923x over previous
//
#include <hip/hip_runtime.h>
#include <hip/hip_bf16.h>

typedef short bf16x8 __attribute__((ext_vector_type(8)));
typedef float f32x4  __attribute__((ext_vector_type(4)));
typedef unsigned short u16;

// float -> bf16 round-to-nearest-even
static __device__ __forceinline__ u16 f2bf(float f) {
    unsigned u = __float_as_uint(f);
    u += 0x7FFFu + ((u >> 16) & 1u);
    return (u16)(u >> 16);
}
static __device__ __forceinline__ float bf2f(u16 b) {
    return __uint_as_float(((unsigned)b) << 16);
}
static __device__ __forceinline__ unsigned pack2(float lo, float hi) {
    return (unsigned)f2bf(lo) | ((unsigned)f2bf(hi) << 16);
}

// ---------------------------------------------------------------------------
// Kernel 1: W' [256 cols][128 k] bf16. W'[c][k] = W1[k][c] (c<128, P half),
// W1[128+k][c-128] (Q half).
// ---------------------------------------------------------------------------
__global__ void prep_w(const float* __restrict__ W1, u16* __restrict__ Wl) {
    int idx = blockIdx.x * 256 + threadIdx.x;   // over W1 flat [256][128]
    if (idx >= 256 * 128) return;
    int r = idx >> 7;     // W1 row 0..255
    int q = idx & 127;    // W1 col 0..127
    int k = (r < 128) ? r : (r - 128);
    int c = (r < 128) ? q : (q + 128);
    Wl[c * 128 + k] = f2bf(W1[idx]);
}

// ---------------------------------------------------------------------------
// Kernel 2: persistent GEMM, PQ[m][c] = sum_k z[m][k]*W'[c][k] (+b1[c], c<128)
// BM=64. W' A-frags hoisted to regs (tile-invariant). z prefetched to regs.
// C staged through LDS -> 512B-contiguous coalesced stores (the R3 bottleneck
// was 8B-stride-512B scattered C stores: 64 lines touched per store instr).
// ---------------------------------------------------------------------------
#define BM 64
__global__ __launch_bounds__(256, 2) void node_gemm(
    const float* __restrict__ z,   // [M][128] fp32
    const u16*   __restrict__ Wl,  // [256][128] bf16
    const float* __restrict__ b1,  // [128]
    u16*         __restrict__ PQ,  // [M][256] bf16
    int M, int ntiles)
{
    __shared__ char As[BM * 256];   // 16 KB: 64 rows x 128 bf16, swizzled
    __shared__ char Cb[BM * 512];   // 32 KB: 64 rows x 256 bf16, swizzled
    const int tid  = threadIdx.x;
    const int lane = tid & 63;
    const int wave = tid >> 6;
    const int g    = lane >> 4;     // k-group 0..3
    const int ln   = lane & 15;
    const int c0   = wave * 64;     // this wave's W'-column slice

    int t = blockIdx.x;
    if (t >= ntiles) return;

    // ---- tile-invariant: W' fragments and bias, held in registers ----
    bf16x8 af[4][4];   // [ks][ci]
    #pragma unroll
    for (int ks = 0; ks < 4; ++ks)
        #pragma unroll
        for (int ci = 0; ci < 4; ++ci)
            af[ks][ci] = *(const bf16x8*)(Wl + (c0 + ci * 16 + ln) * 128 + ks * 32 + g * 8);

    float4 bias[4];
    #pragma unroll
    for (int ci = 0; ci < 4; ++ci) {
        int col = c0 + ci * 16 + g * 4;
        bias[ci] = (col < 128) ? *(const float4*)(b1 + col)
                               : make_float4(0.f, 0.f, 0.f, 0.f);
    }

    float4 r[8];       // z staging regs: 8 float4 chunks (64 rows x 32 ch)

    // ---- prologue: load + stage tile t ----
    {
        int m0 = t * BM;
        #pragma unroll
        for (int i = 0; i < 8; ++i) {
            int ci = tid + i * 256, row = ci >> 5, c4 = ci & 31;
            r[i] = make_float4(0.f, 0.f, 0.f, 0.f);
            if (m0 + row < M)
                r[i] = *(const float4*)(z + (size_t)(m0 + row) * 128 + c4 * 4);
        }
        #pragma unroll
        for (int i = 0; i < 8; ++i) {
            int ci = tid + i * 256, row = ci >> 5, c4 = ci & 31;
            ushort4 b;
            b.x = f2bf(r[i].x); b.y = f2bf(r[i].y);
            b.z = f2bf(r[i].z); b.w = f2bf(r[i].w);
            *(ushort4*)(As + row * 256 + ((c4 * 8) ^ ((row & 7) << 4))) = b;
        }
    }
    __syncthreads();

    while (true) {
        int next = t + gridDim.x;
        bool have = (next < ntiles);

        // ---- issue next tile's z loads (stay in flight through MFMA) ----
        if (have) {
            int m0 = next * BM;
            #pragma unroll
            for (int i = 0; i < 8; ++i) {
                int ci = tid + i * 256, row = ci >> 5, c4 = ci & 31;
                r[i] = make_float4(0.f, 0.f, 0.f, 0.f);
                if (m0 + row < M)
                    r[i] = *(const float4*)(z + (size_t)(m0 + row) * 128 + c4 * 4);
            }
        }

        // ---- MFMA tile t from As ----
        f32x4 acc[4][4];   // [mf][ci]
        #pragma unroll
        for (int mf = 0; mf < 4; ++mf)
            #pragma unroll
            for (int ci = 0; ci < 4; ++ci)
                acc[mf][ci] = (f32x4){0.f, 0.f, 0.f, 0.f};
        #pragma unroll
        for (int ks = 0; ks < 4; ++ks) {
            #pragma unroll
            for (int mf = 0; mf < 4; ++mf) {
                int row  = mf * 16 + ln;
                int byte = row * 256 + ((ks * 64 + g * 16) ^ ((row & 7) << 4));
                bf16x8 b = *(const bf16x8*)(As + byte);
                #pragma unroll
                for (int ci = 0; ci < 4; ++ci)
                    acc[mf][ci] = __builtin_amdgcn_mfma_f32_16x16x32_bf16(
                        af[ks][ci], b, acc[mf][ci], 0, 0, 0);
            }
        }

        // ---- pack acc (+bias) -> Cb, swizzled ----
        #pragma unroll
        for (int mf = 0; mf < 4; ++mf) {
            int node = mf * 16 + ln;
            #pragma unroll
            for (int ci = 0; ci < 4; ++ci) {
                int col = c0 + ci * 16 + g * 4;
                uint2 w;
                w.x = pack2(acc[mf][ci][0] + bias[ci].x,
                            acc[mf][ci][1] + bias[ci].y);
                w.y = pack2(acc[mf][ci][2] + bias[ci].z,
                            acc[mf][ci][3] + bias[ci].w);
                *(uint2*)(Cb + node * 512 + ((col * 2) ^ ((node & 7) << 4))) = w;
            }
        }
        __syncthreads();   // Cb complete; all waves done reading As

        // ---- coalesced C store: 512B contiguous per node row ----
        {
            int m0 = t * BM;
            int chunk = tid & 31;          // 16B chunk within row
            int nb    = tid >> 5;          // node sub-index 0..7
            #pragma unroll
            for (int it = 0; it < 8; ++it) {
                int node = it * 8 + nb;
                uint4 v = *(const uint4*)(Cb + node * 512 +
                                          ((chunk * 16) ^ ((node & 7) << 4)));
                if (m0 + node < M)
                    *(uint4*)(PQ + (size_t)(m0 + node) * 256 + chunk * 8) = v;
            }
        }

        // ---- stage next tile into As (waits only the z loads) ----
        if (have) {
            #pragma unroll
            for (int i = 0; i < 8; ++i) {
                int ci = tid + i * 256, row = ci >> 5, c4 = ci & 31;
                ushort4 b;
                b.x = f2bf(r[i].x); b.y = f2bf(r[i].y);
                b.z = f2bf(r[i].z); b.w = f2bf(r[i].w);
                *(ushort4*)(As + row * 256 + ((c4 * 8) ^ ((row & 7) << 4))) = b;
            }
        } else {
            break;
        }
        __syncthreads();   // As staged, Cb readback done, before next pack
        t = next;
    }
}

// ---------------------------------------------------------------------------
// Kernel 3: out[e] = relu(P[s] + Q[d]) . W2 + b2   (b1 pre-folded into P).
// 16 lanes x 4 edges per thread: 8 independent 16B gathers in flight.
// ---------------------------------------------------------------------------
__global__ __launch_bounds__(256) void edge_mlp(
    const int* __restrict__ ei,    // [2][E] int32
    const u16* __restrict__ PQ,    // [M][256] bf16
    const float* __restrict__ W2,  // [128]
    const float* __restrict__ b2,  // [1]
    float* __restrict__ out,       // [E]
    int E)
{
    int gid = blockIdx.x * 256 + threadIdx.x;
    int e0  = (gid >> 4) * 4;
    int sub = gid & 15;
    if (e0 >= E) return;

    float4 w2a = *(const float4*)(W2 + sub * 8);
    float4 w2b = *(const float4*)(W2 + sub * 8 + 4);
    float ww[8] = {w2a.x, w2a.y, w2a.z, w2a.w, w2b.x, w2b.y, w2b.z, w2b.w};
    float bias = b2[0];

    if (e0 + 3 < E) {
        int4 s = *(const int4*)(ei + e0);
        int4 d = *(const int4*)(ei + E + e0);
        uint4 p0 = *(const uint4*)(PQ + (size_t)s.x * 256 + sub * 8);
        uint4 p1 = *(const uint4*)(PQ + (size_t)s.y * 256 + sub * 8);
        uint4 p2 = *(const uint4*)(PQ + (size_t)s.z * 256 + sub * 8);
        uint4 p3 = *(const uint4*)(PQ + (size_t)s.w * 256 + sub * 8);
        uint4 q0 = *(const uint4*)(PQ + (size_t)d.x * 256 + 128 + sub * 8);
        uint4 q1 = *(const uint4*)(PQ + (size_t)d.y * 256 + 128 + sub * 8);
        uint4 q2 = *(const uint4*)(PQ + (size_t)d.z * 256 + 128 + sub * 8);
        uint4 q3 = *(const uint4*)(PQ + (size_t)d.w * 256 + 128 + sub * 8);

        float a0 = 0.f, a1 = 0.f, a2 = 0.f, a3 = 0.f;
        const u16* pu0 = (const u16*)&p0; const u16* qu0 = (const u16*)&q0;
        const u16* pu1 = (const u16*)&p1; const u16* qu1 = (const u16*)&q1;
        const u16* pu2 = (const u16*)&p2; const u16* qu2 = (const u16*)&q2;
        const u16* pu3 = (const u16*)&p3; const u16* qu3 = (const u16*)&q3;
        #pragma unroll
        for (int j = 0; j < 8; ++j) {
            a0 = fmaf(fmaxf(bf2f(pu0[j]) + bf2f(qu0[j]), 0.f), ww[j], a0);
            a1 = fmaf(fmaxf(bf2f(pu1[j]) + bf2f(qu1[j]), 0.f), ww[j], a1);
            a2 = fmaf(fmaxf(bf2f(pu2[j]) + bf2f(qu2[j]), 0.f), ww[j], a2);
            a3 = fmaf(fmaxf(bf2f(pu3[j]) + bf2f(qu3[j]), 0.f), ww[j], a3);
        }
        #pragma unroll
        for (int m = 1; m < 16; m <<= 1) {
            a0 += __shfl_xor(a0, m);
            a1 += __shfl_xor(a1, m);
            a2 += __shfl_xor(a2, m);
            a3 += __shfl_xor(a3, m);
        }
        if (sub == 0) {
            float4 o = make_float4(a0 + bias, a1 + bias, a2 + bias, a3 + bias);
            *(float4*)(out + e0) = o;
        }
    } else {
        for (int k = 0; k < 4; ++k) {
            int e = e0 + k;
            if (e >= E) break;
            int sn = ei[e], dn = ei[E + e];
            uint4 p = *(const uint4*)(PQ + (size_t)sn * 256 + sub * 8);
            uint4 q = *(const uint4*)(PQ + (size_t)dn * 256 + 128 + sub * 8);
            const u16* pu = (const u16*)&p; const u16* qu = (const u16*)&q;
            float a = 0.f;
            #pragma unroll
            for (int j = 0; j < 8; ++j)
                a = fmaf(fmaxf(bf2f(pu[j]) + bf2f(qu[j]), 0.f), ww[j], a);
            #pragma unroll
            for (int m = 1; m < 16; m <<= 1) a += __shfl_xor(a, m);
            if (sub == 0) out[e] = a + bias;
        }
    }
}

// ---------------------------------------------------------------------------
extern "C" void kernel_launch(void* const* d_in, const int* in_sizes, int n_in,
                              void* d_out, int out_size, void* d_ws, size_t ws_size,
                              hipStream_t stream) {
    const float* z  = (const float*)d_in[0];
    const int*   ei = (const int*)d_in[1];
    const float* W1 = (const float*)d_in[2];
    const float* b1 = (const float*)d_in[3];
    const float* W2 = (const float*)d_in[4];
    const float* b2 = (const float*)d_in[5];
    float* out = (float*)d_out;

    const int M = in_sizes[0] / 128;   // 100000 nodes
    const int E = in_sizes[1] / 2;     // 640000 edges

    u16* Wl = (u16*)d_ws;                          // 64 KB
    u16* PQ = (u16*)((char*)d_ws + 65536);         // M*256*2 B = 51.2 MB

    hipLaunchKernelGGL(prep_w, dim3(128), dim3(256), 0, stream, W1, Wl);

    int ntiles = (M + BM - 1) / BM;
    int gb = ntiles < 512 ? ntiles : 512;
    hipLaunchKernelGGL(node_gemm, dim3(gb), dim3(256), 0, stream,
                       z, Wl, b1, PQ, M, ntiles);

    int eb = ((E + 3) / 4 * 16 + 255) / 256;
    hipLaunchKernelGGL(edge_mlp, dim3(eb), dim3(256), 0, stream,
                       ei, PQ, W2, b2, out, E);
}